// Round 10
// baseline (303.930 us; speedup 1.0000x reference)
//
#include <hip/hip_runtime.h>
#include <math.h>

// ---------------------------------------------------------------------------
// DeformableFeatureAggregation — MI355X
// Pipeline (5 launches):
//   k_transpose_all : feat L0..L3 (6,256,H,W) fp32 -> featF (6,H,W,256) fp8 e4m3
//   k_prep_pack     : iw->Ab bf16 ; Bb bf16 N-major in TASK-PERMUTED row order
//                     (row j' = g*328 + t, t=(p*6+c)*4+l; learn rows appended);
//                     W_out->Wob ; biasP (permuted b_wts / b_learn)
//   k_wts_mfma      : MFMA; epilogue stores exp(acc+biasP) bf16 task-ordered
//                     (softmax without max-subtract: |logit|<~3) + learn fp32
//   k_sample        : per-anchor block: LDS copy (no perm), sum+normalize,
//                     projection, task tables, fp8 gather (quarter-wave/uint4)
//   k_out_mfma      : MFMA out = featsB @ W_out^T + b_out + iw (fp32)
// Workspace (float offsets):
//   featF  : bytes 0..22978560            (f 0..5744640)
//   logitsE: f 5744640   (4096x2624 ush)  -> 11118592   [exp'd, task order]
//   featsB : f 11118592  (4096x256 ush)   -> 11642880
//   learn  : f 11642880  (4096x18 f)      -> 11716608
//   Ab     : f 11716608  (4096x256 ush)   -> 12240896
//   Bb     : f 12240896  (2688x256 ush)   -> 12584960
//   Wob    : f 12584960  (256x256 ush)    -> 12617728
//   biasP  : f 12617728  (2688 f)         -> 12620416   (~50 MB)
// ---------------------------------------------------------------------------

#define FT_L0 0
#define FT_L1 17301504
#define FT_L2 21626880
#define FT_L3 22708224
#define WS_LOGE 5744640
#define WS_FEATB 11118592
#define WS_LEARN 11642880
#define WS_AB 11716608
#define WS_BB 12240896
#define WS_WOB 12584960
#define WS_BIASP 12617728

typedef float v2f __attribute__((ext_vector_type(2)));
typedef __attribute__((ext_vector_type(8))) short bf16x8;
typedef __attribute__((ext_vector_type(4))) float f32x4;

__device__ const float FIXS[7][3] = {
    {0.f, 0.f, 0.f},  {0.45f, 0.f, 0.f}, {-0.45f, 0.f, 0.f}, {0.f, 0.45f, 0.f},
    {0.f, -0.45f, 0.f}, {0.f, 0.f, 0.45f}, {0.f, 0.f, -0.45f}};

__device__ __forceinline__ unsigned int f2bf(float f) {
  unsigned int u = __float_as_uint(f);
  u += 0x7fffu + ((u >> 16) & 1u);  // RTNE
  return u >> 16;
}
__device__ __forceinline__ float bf2f(unsigned short u) {
  return __uint_as_float(((unsigned int)u) << 16);
}

// All 4 levels: (6,256,H,W) fp32 -> (6,H,W,256) fp8 e4m3. grid (12, 64, 48)
__global__ __launch_bounds__(256) void k_transpose_all(
    const float* __restrict__ f0, const float* __restrict__ f1,
    const float* __restrict__ f2, const float* __restrict__ f3,
    unsigned char* __restrict__ featF) {
  const int bx = blockIdx.x;
  const float* src;
  unsigned char* dst;
  int H, W, xt;
  if (bx < 6)       { src = f0; dst = featF + FT_L0; H = 64; W = 176; xt = bx * 32; }
  else if (bx < 9)  { src = f1; dst = featF + FT_L1; H = 32; W = 88;  xt = (bx - 6) * 32; }
  else if (bx < 11) { src = f2; dst = featF + FT_L2; H = 16; W = 44;  xt = (bx - 9) * 32; }
  else              { src = f3; dst = featF + FT_L3; H = 8;  W = 22;  xt = 0; }
  const int y = blockIdx.y;
  if (y >= H) return;
  __shared__ float tile[32][33];
  const int tid = threadIdx.x;
  const int i = tid & 31;
  const int j = tid >> 5;
  const int c = blockIdx.z >> 3;
  const int cht = (blockIdx.z & 7) * 32;
#pragma unroll
  for (int jj = j; jj < 32; jj += 8) {
    int x = xt + i;
    float v = 0.f;
    if (x < W) v = src[((c * 256 + cht + jj) * H + y) * W + x];
    tile[jj][i] = v;
  }
  __syncthreads();
  const int q = tid & 7;
  const int xw = tid >> 3;
  const int x = xt + xw;
  if (x < W) {
    const float v0 = tile[q * 4 + 0][xw];
    const float v1 = tile[q * 4 + 1][xw];
    const float v2 = tile[q * 4 + 2][xw];
    const float v3 = tile[q * 4 + 3][xw];
    int pk = __builtin_amdgcn_cvt_pk_fp8_f32(v0, v1, 0, false);
    pk = __builtin_amdgcn_cvt_pk_fp8_f32(v2, v3, pk, true);
    *(unsigned int*)(dst + (((c * H + y) * W + x) * 256) + cht + q * 4) =
        (unsigned int)pk;
  }
}

// Map permuted output row r' -> source: mode 0 = W_wts col srcj, 1 = W_learn
// col srcj, 2 = zero. r' = g*328 + t, t=(p*6+c)*4+l <-> s = c*52+l*13+p.
__device__ __forceinline__ int rowmap(int rp, int* srcj) {
  if (rp < 2624) {
    const int g = rp / 328;
    const int u = rp - g * 328;
    if (u < 312) {
      const int pc = u >> 2, l = u & 3;
      const int p = pc / 6, c = pc - p * 6;
      *srcj = (c * 52 + l * 13 + p) * 8 + g;
      return 0;
    }
    return 2;
  }
  if (rp < 2642) { *srcj = rp - 2624; return 1; }
  return 2;
}

// Fused packing. grid 1771:
//  bx<1024: Ab ; <1696: Bb tile (84 x 8) ; <1760: Wob tile ; else biasP.
__global__ __launch_bounds__(256) void k_prep_pack(
    const float* __restrict__ iw, const float* __restrict__ Ww,
    const float* __restrict__ Wl, const float* __restrict__ Wo,
    const float* __restrict__ bw, const float* __restrict__ bl,
    unsigned short* __restrict__ Ab, unsigned short* __restrict__ Bb,
    unsigned short* __restrict__ Wob, float* __restrict__ biasP) {
  __shared__ unsigned short tile[32][33];
  const int tid = threadIdx.x;
  const int bx = blockIdx.x;
  if (bx < 1024) {
    const int i = bx * 256 + tid;
    const float4 v = ((const float4*)iw)[i];
    uint2 o;
    o.x = f2bf(v.x) | (f2bf(v.y) << 16);
    o.y = f2bf(v.z) | (f2bf(v.w) << 16);
    ((uint2*)Ab)[i] = o;
    return;
  }
  const int i = tid & 31;
  const int r = tid >> 5;
  if (bx < 1696) {
    const int idx = bx - 1024;
    const int j0 = (idx % 84) * 32;
    const int k0 = (idx / 84) * 32;
    int srcj = 0;
    const int mode = rowmap(j0 + i, &srcj);
#pragma unroll
    for (int rr = r; rr < 32; rr += 8) {
      const int k = k0 + rr;
      float v = 0.f;
      if (mode == 0) v = Ww[k * 2496 + srcj];
      else if (mode == 1) v = Wl[k * 18 + srcj];
      tile[rr][i] = (unsigned short)f2bf(v);
    }
    __syncthreads();
#pragma unroll
    for (int rr = r; rr < 32; rr += 8)
      Bb[(j0 + rr) * 256 + k0 + i] = tile[i][rr];
  } else if (bx < 1760) {
    const int idx = bx - 1696;
    const int j0 = (idx & 7) * 32;
    const int k0 = (idx >> 3) * 32;
#pragma unroll
    for (int rr = r; rr < 32; rr += 8)
      tile[rr][i] = (unsigned short)f2bf(Wo[(k0 + rr) * 256 + j0 + i]);
    __syncthreads();
#pragma unroll
    for (int rr = r; rr < 32; rr += 8)
      Wob[(j0 + rr) * 256 + k0 + i] = tile[i][rr];
  } else {
    const int rp = (bx - 1760) * 256 + tid;
    if (rp < 2688) {
      int srcj = 0;
      const int mode = rowmap(rp, &srcj);
      float b = 0.f;
      if (mode == 0) b = bw[(srcj >> 3)];
      else if (mode == 1) b = bl[srcj];
      biasP[rp] = b;
    }
  }
}

// MFMA GEMM over permuted Bb. grid (42,64).
// cols <2624 -> exp(acc+biasP) bf16 (task-ordered softmax numerator);
// cols 2624..2641 -> sigmoid -> learn fp32.
__global__ __launch_bounds__(256) void k_wts_mfma(
    const unsigned short* __restrict__ Ab, const unsigned short* __restrict__ Bb,
    const float* __restrict__ biasP,
    unsigned short* __restrict__ logitsE, float* __restrict__ learn) {
  const int tid = threadIdx.x;
  const int w = tid >> 6, lane = tid & 63;
  const int ml = lane & 15, q = lane >> 4;
  const int n0 = blockIdx.x * 64;
  const int m0 = blockIdx.y * 64;
  f32x4 acc[4] = {{0.f, 0.f, 0.f, 0.f}, {0.f, 0.f, 0.f, 0.f},
                  {0.f, 0.f, 0.f, 0.f}, {0.f, 0.f, 0.f, 0.f}};
  const unsigned short* Ap = Ab + (m0 + w * 16 + ml) * 256 + q * 8;
  const unsigned short* Bp = Bb + (n0 + ml) * 256 + q * 8;
#pragma unroll
  for (int kk = 0; kk < 8; ++kk) {
    const bf16x8 a = *(const bf16x8*)(Ap + kk * 32);
#pragma unroll
    for (int nt = 0; nt < 4; ++nt) {
      const bf16x8 b = *(const bf16x8*)(Bp + nt * 16 * 256 + kk * 32);
      acc[nt] = __builtin_amdgcn_mfma_f32_16x16x32_bf16(a, b, acc[nt], 0, 0, 0);
    }
  }
  const int rowb = m0 + w * 16 + q * 4;
#pragma unroll
  for (int nt = 0; nt < 4; ++nt) {
    const int col = n0 + nt * 16 + ml;
    const float b = biasP[col];
    if (col < 2624) {
#pragma unroll
      for (int r = 0; r < 4; ++r)
        logitsE[(rowb + r) * 2624 + col] = (unsigned short)f2bf(__expf(acc[nt][r] + b));
    } else if (col < 2642) {
#pragma unroll
      for (int r = 0; r < 4; ++r) {
        float v = fminf(fmaxf(acc[nt][r] + b, -9.21f), 9.21f);
        learn[(rowb + r) * 18 + (col - 2624)] = 1.f / (1.f + expf(-v)) - 0.5f;
      }
    }
  }
}

// Fused per-anchor sampler. grid 4096 x 256.
__global__ __launch_bounds__(256, 8) void k_sample(
    const float* __restrict__ anchor, const unsigned short* __restrict__ logitsE,
    const float* __restrict__ learn_g, const unsigned char* __restrict__ featF,
    const float* __restrict__ proj, const float* __restrict__ wh,
    unsigned short* __restrict__ featsB) {
  const int n = blockIdx.x;
  const int tid = threadIdx.x;
  const int lane = tid & 63;
  const int wave = tid >> 6;
  __shared__ unsigned short s_w[8 * 328];  // exp'd weights [g][t], task order
  __shared__ float s_p2d[78][2];
  __shared__ float s_learn[18];
  __shared__ int4 s_off[320];
  __shared__ float4 s_wt[320];
  __shared__ float s_red[4][256];

  // phase 1: straight coalesced copy (already exp'd + task-ordered)
  {
    const unsigned int* src = (const unsigned int*)(logitsE + n * 2624);
    unsigned int* dstw = (unsigned int*)s_w;
    for (int i = tid; i < 1312; i += 256) dstw[i] = src[i];
  }
  if (tid < 18) s_learn[tid] = learn_g[n * 18 + tid];
  __syncthreads();

  // phase 2: normalize per group (sum over 312 valid tasks)
#pragma unroll
  for (int gg = 0; gg < 2; ++gg) {
    unsigned short* row = &s_w[(wave * 2 + gg) * 328];
    float l[5];
    float sum = 0.f;
#pragma unroll
    for (int i = 0; i < 5; ++i) {
      const int s = lane + i * 64;
      l[i] = (s < 312) ? bf2f(row[s]) : 0.f;
      sum += l[i];
    }
    for (int off = 32; off; off >>= 1) sum += __shfl_xor(sum, off);
    const float inv = 1.f / sum;
#pragma unroll
    for (int i = 0; i < 5; ++i) {
      const int s = lane + i * 64;
      if (s < 312) row[s] = (unsigned short)f2bf(l[i] * inv);
    }
  }

  // phase 3: projection of 78 (pt,cam) pairs
  if (tid < 78) {
    const int p = tid / 6, c = tid % 6;
    const float* an = anchor + n * 11;
    float qw = an[6], qx = an[7], qy = an[8], qz = an[9];
    const float qinv = 1.f / sqrtf(qw * qw + qx * qx + qy * qy + qz * qz);
    qw *= qinv; qx *= qinv; qy *= qinv; qz *= qinv;
    const float R00 = 1.f - 2.f * (qy * qy + qz * qz), R01 = 2.f * (qx * qy - qw * qz), R02 = 2.f * (qx * qz + qw * qy);
    const float R10 = 2.f * (qx * qy + qw * qz), R11 = 1.f - 2.f * (qx * qx + qz * qz), R12 = 2.f * (qy * qz - qw * qx);
    const float R20 = 2.f * (qx * qz - qw * qy), R21 = 2.f * (qy * qz + qw * qx), R22 = 1.f - 2.f * (qx * qx + qy * qy);
    float s0, s1, s2;
    if (p < 7) {
      s0 = FIXS[p][0]; s1 = FIXS[p][1]; s2 = FIXS[p][2];
    } else {
      const int b = (p - 7) * 3;
      s0 = s_learn[b]; s1 = s_learn[b + 1]; s2 = s_learn[b + 2];
    }
    const float vx = s0 * an[3], vy = s1 * an[4], vz = s2 * an[5];
    const float kx = R00 * vx + R10 * vy + R20 * vz + an[0];
    const float ky = R01 * vx + R11 * vy + R21 * vz + an[1];
    const float kz = R02 * vx + R12 * vy + R22 * vz + an[2];
    const float* P = proj + c * 16;
    const float h0 = P[0] * kx + P[1] * ky + P[2] * kz + P[3];
    const float h1 = P[4] * kx + P[5] * ky + P[6] * kz + P[7];
    const float h2 = P[8] * kx + P[9] * ky + P[10] * kz + P[11];
    const float zz = fmaxf(h2, 1e-5f);
    float px = h0 / zz / wh[c * 2 + 0];
    float py = h1 / zz / wh[c * 2 + 1];
    px = fminf(fmaxf(px, 0.f), 0.9999f);
    py = fminf(fmaxf(py, 0.f), 0.9999f);
    s_p2d[tid][0] = px;
    s_p2d[tid][1] = py;
  }
  __syncthreads();

  // phase 4: per-task corner BYTE offsets + bilinear weights (pad to 320)
  {
    constexpr int LBB[4] = {FT_L0, FT_L1, FT_L2, FT_L3};
    constexpr int CSB[4] = {2883584, 720896, 180224, 45056};  // H*W*256
    for (int t = tid; t < 320; t += 256) {
      const int pc = t >> 2, l = t & 3;
      if (pc >= 78) {
        s_off[t] = make_int4(0, 0, 0, 0);
        s_wt[t] = make_float4(0.f, 0.f, 0.f, 0.f);
        continue;
      }
      const int c = pc % 6;
      const int H = 64 >> l, W = 176 >> l;
      const float fx = s_p2d[pc][0] * (float)W - 0.5f;
      const float fy = s_p2d[pc][1] * (float)H - 0.5f;
      const float x0f = floorf(fx), y0f = floorf(fy);
      const float wx = fx - x0f, wy = fy - y0f;
      const int x0 = (int)x0f, y0 = (int)y0f;
      const float mx0 = (x0 >= 0) ? 1.f : 0.f;
      const float mx1 = (x0 + 1 < W) ? 1.f : 0.f;
      const float my0 = (y0 >= 0) ? 1.f : 0.f;
      const float my1 = (y0 + 1 < H) ? 1.f : 0.f;
      const int cx0 = max(x0, 0), cx1 = min(x0 + 1, W - 1);
      const int cy0 = max(y0, 0), cy1 = min(y0 + 1, H - 1);
      const int base = LBB[l] + c * CSB[l];
      int4 o;
      o.x = base + (cy0 * W + cx0) * 256;
      o.y = base + (cy0 * W + cx1) * 256;
      o.z = base + (cy1 * W + cx0) * 256;
      o.w = base + (cy1 * W + cx1) * 256;
      s_off[t] = o;
      float4 w4;
      w4.x = (1.f - wx) * (1.f - wy) * mx0 * my0;
      w4.y = wx * (1.f - wy) * mx1 * my0;
      w4.z = (1.f - wx) * wy * mx0 * my1;
      w4.w = wx * wy * mx1 * my1;
      s_wt[t] = w4;
    }
  }
  __syncthreads();

  // phase 5: fp8 gather. quarter-wave = one pc; 16 fp8 channels per lane.
  const int q = lane >> 4;
  const int ql = lane & 15;
  const int chb = ql * 16;
  const int g = ql >> 1;
  v2f acc[8];
#pragma unroll
  for (int k = 0; k < 8; ++k) acc[k] = (v2f){0.f, 0.f};
  const unsigned char* fb = featF;
  const unsigned short* wrow = &s_w[g * 328];
  const int pcb = wave * 4 + q;
#pragma unroll
  for (int it = 0; it < 5; ++it) {
    const int pc = pcb + it * 16;
    const int t0 = pc * 4;
    const uint2 wq = *(const uint2*)&wrow[t0];
    float wgl[4];
    wgl[0] = __uint_as_float(wq.x << 16);
    wgl[1] = __uint_as_float(wq.x & 0xffff0000u);
    wgl[2] = __uint_as_float(wq.y << 16);
    wgl[3] = __uint_as_float(wq.y & 0xffff0000u);
#pragma unroll
    for (int l4 = 0; l4 < 4; ++l4) {
      const int t = t0 + l4;
      const int4 o = s_off[t];
      const float4 bw = s_wt[t];
      const float wg = wgl[l4];
      const uint4 u0 = *(const uint4*)(fb + (o.x + chb));
      const uint4 u1 = *(const uint4*)(fb + (o.y + chb));
      const uint4 u2 = *(const uint4*)(fb + (o.z + chb));
      const uint4 u3 = *(const uint4*)(fb + (o.w + chb));
      const float s0 = bw.x * wg, s1 = bw.y * wg, s2 = bw.z * wg, s3 = bw.w * wg;
      const v2f w0 = {s0, s0}, w1 = {s1, s1}, w2 = {s2, s2}, w3 = {s3, s3};
      acc[0] += __builtin_amdgcn_cvt_pk_f32_fp8((int)u0.x, false) * w0;
      acc[1] += __builtin_amdgcn_cvt_pk_f32_fp8((int)u0.x, true)  * w0;
      acc[2] += __builtin_amdgcn_cvt_pk_f32_fp8((int)u0.y, false) * w0;
      acc[3] += __builtin_amdgcn_cvt_pk_f32_fp8((int)u0.y, true)  * w0;
      acc[4] += __builtin_amdgcn_cvt_pk_f32_fp8((int)u0.z, false) * w0;
      acc[5] += __builtin_amdgcn_cvt_pk_f32_fp8((int)u0.z, true)  * w0;
      acc[6] += __builtin_amdgcn_cvt_pk_f32_fp8((int)u0.w, false) * w0;
      acc[7] += __builtin_amdgcn_cvt_pk_f32_fp8((int)u0.w, true)  * w0;
      acc[0] += __builtin_amdgcn_cvt_pk_f32_fp8((int)u1.x, false) * w1;
      acc[1] += __builtin_amdgcn_cvt_pk_f32_fp8((int)u1.x, true)  * w1;
      acc[2] += __builtin_amdgcn_cvt_pk_f32_fp8((int)u1.y, false) * w1;
      acc[3] += __builtin_amdgcn_cvt_pk_f32_fp8((int)u1.y, true)  * w1;
      acc[4] += __builtin_amdgcn_cvt_pk_f32_fp8((int)u1.z, false) * w1;
      acc[5] += __builtin_amdgcn_cvt_pk_f32_fp8((int)u1.z, true)  * w1;
      acc[6] += __builtin_amdgcn_cvt_pk_f32_fp8((int)u1.w, false) * w1;
      acc[7] += __builtin_amdgcn_cvt_pk_f32_fp8((int)u1.w, true)  * w1;
      acc[0] += __builtin_amdgcn_cvt_pk_f32_fp8((int)u2.x, false) * w2;
      acc[1] += __builtin_amdgcn_cvt_pk_f32_fp8((int)u2.x, true)  * w2;
      acc[2] += __builtin_amdgcn_cvt_pk_f32_fp8((int)u2.y, false) * w2;
      acc[3] += __builtin_amdgcn_cvt_pk_f32_fp8((int)u2.y, true)  * w2;
      acc[4] += __builtin_amdgcn_cvt_pk_f32_fp8((int)u2.z, false) * w2;
      acc[5] += __builtin_amdgcn_cvt_pk_f32_fp8((int)u2.z, true)  * w2;
      acc[6] += __builtin_amdgcn_cvt_pk_f32_fp8((int)u2.w, false) * w2;
      acc[7] += __builtin_amdgcn_cvt_pk_f32_fp8((int)u2.w, true)  * w2;
      acc[0] += __builtin_amdgcn_cvt_pk_f32_fp8((int)u3.x, false) * w3;
      acc[1] += __builtin_amdgcn_cvt_pk_f32_fp8((int)u3.x, true)  * w3;
      acc[2] += __builtin_amdgcn_cvt_pk_f32_fp8((int)u3.y, false) * w3;
      acc[3] += __builtin_amdgcn_cvt_pk_f32_fp8((int)u3.y, true)  * w3;
      acc[4] += __builtin_amdgcn_cvt_pk_f32_fp8((int)u3.z, false) * w3;
      acc[5] += __builtin_amdgcn_cvt_pk_f32_fp8((int)u3.z, true)  * w3;
      acc[6] += __builtin_amdgcn_cvt_pk_f32_fp8((int)u3.w, false) * w3;
      acc[7] += __builtin_amdgcn_cvt_pk_f32_fp8((int)u3.w, true)  * w3;
    }
  }
#pragma unroll
  for (int k = 0; k < 8; ++k) {
    v2f b;
    b.x = __shfl_xor(acc[k].x, 16);
    b.y = __shfl_xor(acc[k].y, 16);
    acc[k] += b;
    b.x = __shfl_xor(acc[k].x, 32);
    b.y = __shfl_xor(acc[k].y, 32);
    acc[k] += b;
  }
  if (lane < 16) {
    float* dst = &s_red[wave][ql * 16];
    *(float4*)(dst + 0)  = make_float4(acc[0].x, acc[0].y, acc[1].x, acc[1].y);
    *(float4*)(dst + 4)  = make_float4(acc[2].x, acc[2].y, acc[3].x, acc[3].y);
    *(float4*)(dst + 8)  = make_float4(acc[4].x, acc[4].y, acc[5].x, acc[5].y);
    *(float4*)(dst + 12) = make_float4(acc[6].x, acc[6].y, acc[7].x, acc[7].y);
  }
  __syncthreads();
  {
    const float sum = s_red[0][tid] + s_red[1][tid] + s_red[2][tid] + s_red[3][tid];
    featsB[n * 256 + tid] = (unsigned short)f2bf(sum);
  }
}

// MFMA GEMM: out = featsB(4096x256) @ Wob^T + b_out + resid. grid (4,64)
__global__ __launch_bounds__(256) void k_out_mfma(
    const unsigned short* __restrict__ Ab, const unsigned short* __restrict__ Bb,
    const float* __restrict__ bias, const float* __restrict__ resid,
    float* __restrict__ out) {
  const int tid = threadIdx.x;
  const int w = tid >> 6, lane = tid & 63;
  const int ml = lane & 15, q = lane >> 4;
  const int n0 = blockIdx.x * 64;
  const int m0 = blockIdx.y * 64;
  f32x4 acc[4] = {{0.f, 0.f, 0.f, 0.f}, {0.f, 0.f, 0.f, 0.f},
                  {0.f, 0.f, 0.f, 0.f}, {0.f, 0.f, 0.f, 0.f}};
  const unsigned short* Ap = Ab + (m0 + w * 16 + ml) * 256 + q * 8;
  const unsigned short* Bp = Bb + (n0 + ml) * 256 + q * 8;
#pragma unroll
  for (int kk = 0; kk < 8; ++kk) {
    const bf16x8 a = *(const bf16x8*)(Ap + kk * 32);
#pragma unroll
    for (int nt = 0; nt < 4; ++nt) {
      const bf16x8 b = *(const bf16x8*)(Bp + nt * 16 * 256 + kk * 32);
      acc[nt] = __builtin_amdgcn_mfma_f32_16x16x32_bf16(a, b, acc[nt], 0, 0, 0);
    }
  }
  const int rowb = m0 + w * 16 + q * 4;
#pragma unroll
  for (int nt = 0; nt < 4; ++nt) {
    const int col = n0 + nt * 16 + ml;
    const float b = bias[col];
#pragma unroll
    for (int r = 0; r < 4; ++r) {
      const int row = rowb + r;
      out[row * 256 + col] = acc[nt][r] + b + resid[row * 256 + col];
    }
  }
}

extern "C" void kernel_launch(void* const* d_in, const int* in_sizes, int n_in,
                              void* d_out, int out_size, void* d_ws, size_t ws_size,
                              hipStream_t stream) {
  (void)in_sizes; (void)n_in; (void)out_size; (void)ws_size;
  const float* iw      = (const float*)d_in[1];
  const float* anchor  = (const float*)d_in[2];
  const float* f0      = (const float*)d_in[3];
  const float* f1      = (const float*)d_in[4];
  const float* f2      = (const float*)d_in[5];
  const float* f3      = (const float*)d_in[6];
  const float* proj    = (const float*)d_in[7];
  const float* wh      = (const float*)d_in[8];
  const float* W_learn = (const float*)d_in[9];
  const float* b_learn = (const float*)d_in[10];
  const float* W_wts   = (const float*)d_in[11];
  const float* b_wts   = (const float*)d_in[12];
  const float* W_out   = (const float*)d_in[13];
  const float* b_out   = (const float*)d_in[14];
  float* out = (float*)d_out;
  float* ws = (float*)d_ws;
  unsigned char*  featF   = (unsigned char*)ws;
  unsigned short* logitsE = (unsigned short*)(ws + WS_LOGE);
  unsigned short* featsB  = (unsigned short*)(ws + WS_FEATB);
  float*          learn   = ws + WS_LEARN;
  unsigned short* Ab      = (unsigned short*)(ws + WS_AB);
  unsigned short* Bb      = (unsigned short*)(ws + WS_BB);
  unsigned short* Wob     = (unsigned short*)(ws + WS_WOB);
  float*          biasP   = ws + WS_BIASP;

  k_transpose_all<<<dim3(12, 64, 48), 256, 0, stream>>>(f0, f1, f2, f3, featF);
  k_prep_pack<<<1771, 256, 0, stream>>>(iw, W_wts, W_learn, W_out, b_wts, b_learn,
                                        Ab, Bb, Wob, biasP);
  k_wts_mfma<<<dim3(42, 64), 256, 0, stream>>>(Ab, Bb, biasP, logitsE, learn);
  k_sample<<<4096, 256, 0, stream>>>(anchor, logitsE, learn, featF, proj, wh, featsB);
  k_out_mfma<<<dim3(4, 64), 256, 0, stream>>>(featsB, Wob, b_out, iw, out);
}